// Round 1
// baseline (732.949 us; speedup 1.0000x reference)
//
#include <hip/hip_runtime.h>
#include <cstddef>

// Problem constants
#define BB 16
#define HH 256
#define CC 128
#define WW 128

typedef _Float16 f16;
typedef _Float16 f16x8 __attribute__((ext_vector_type(8)));
typedef _Float16 f16x4 __attribute__((ext_vector_type(4)));
typedef _Float16 f16x2 __attribute__((ext_vector_type(2)));
typedef float f32x4 __attribute__((ext_vector_type(4)));

#define LD1 136   // padded ld (f16) for K=128 operands: 272B stride -> 2-way max on b128 frag reads
#define LDX 264   // padded ld (f16) for K=256 X operand in P1
#define REG 17920 // f16 elems per LDS region

__device__ __forceinline__ void zero_acc(f32x4 acc[4][4]) {
#pragma unroll
    for (int i = 0; i < 4; ++i)
#pragma unroll
        for (int j = 0; j < 4; ++j) acc[i][j] = (f32x4){0.f, 0.f, 0.f, 0.f};
}

// C[128x128] += A(128xK, lds) * B^T-layout(Bt[n][k], lds). Wave covers 64x64 (4x4 tiles 16x16).
__device__ __forceinline__ void gemm_ab(const f16* __restrict__ A, int lda,
                                        const f16* __restrict__ B, int ldb,
                                        int K, int m0, int n0, int l15, int quad,
                                        f32x4 acc[4][4]) {
    for (int kc = 0; kc < K; kc += 32) {
        f16x8 af[4], bf[4];
        const f16* ap = A + (size_t)(m0 + l15) * lda + kc + quad * 8;
        const f16* bp = B + (size_t)(n0 + l15) * ldb + kc + quad * 8;
#pragma unroll
        for (int t = 0; t < 4; ++t) {
            af[t] = *(const f16x8*)(ap + t * 16 * lda);
            bf[t] = *(const f16x8*)(bp + t * 16 * ldb);
        }
#pragma unroll
        for (int mt = 0; mt < 4; ++mt)
#pragma unroll
            for (int nt = 0; nt < 4; ++nt)
                acc[mt][nt] = __builtin_amdgcn_mfma_f32_16x16x32_f16(af[mt], bf[nt], acc[mt][nt], 0, 0, 0);
    }
}

// C[128x128] += A(128x128, lds, ld=lda) * X(128x128) where X is staged SUBTILED in LDS:
// subtile (c2q=c2>>2, hq=h>>4) is a 4x16 row-major tile at f16 offset (c2q*8+hq)*68,
// element (c2&3, h&15) at +(c2&3)*16+(h&15). B fragments fetched with ds_read_b64_tr_b16:
// the 16 lanes of each quad supply linear addresses over one subtile; lane l15 receives
// column l15, elem j = row j  =>  bv[4*tau+j] = X[kc+quad*8+4*tau+j][n0+nt*16+l15].
__device__ __forceinline__ void gemm_a_btr(const f16* __restrict__ A, int lda,
                                           const f16* __restrict__ XS,
                                           int m0, int n0, int l15, int quad,
                                           f32x4 acc[4][4]) {
    const unsigned xb = (unsigned)(size_t)XS;   // LDS byte address (low 32 bits of flat)
    for (int kc = 0; kc < 128; kc += 32) {
        f16x8 af[4];
        const f16* ap = A + (size_t)(m0 + l15) * lda + kc + quad * 8;
#pragma unroll
        for (int t = 0; t < 4; ++t) af[t] = *(const f16x8*)(ap + t * 16 * lda);
        int i0 = (kc >> 2) + 2 * quad;          // c2q for tau=0
        f16x4 blo[4], bhi[4];
#pragma unroll
        for (int nt = 0; nt < 4; ++nt) {
            unsigned idx0 = (unsigned)(i0 * 8 + (n0 >> 4) + nt);
            unsigned a0 = xb + (idx0 * 68u + (unsigned)l15 * 4u) * 2u;
            unsigned a1 = a0 + 8u * 68u * 2u;   // tau=1: c2q+1 -> idx+8
            asm volatile("ds_read_b64_tr_b16 %0, %1" : "=v"(blo[nt]) : "v"(a0));
            asm volatile("ds_read_b64_tr_b16 %0, %1" : "=v"(bhi[nt]) : "v"(a1));
        }
        asm volatile("s_waitcnt lgkmcnt(0)" ::: "memory");
        __builtin_amdgcn_sched_barrier(0);
#pragma unroll
        for (int nt = 0; nt < 4; ++nt) {
            f16x8 bv = __builtin_shufflevector(blo[nt], bhi[nt], 0, 1, 2, 3, 4, 5, 6, 7);
#pragma unroll
            for (int mt = 0; mt < 4; ++mt)
                acc[mt][nt] = __builtin_amdgcn_mfma_f32_16x16x32_f16(af[mt], bv, acc[mt][nt], 0, 0, 0);
        }
    }
}

// Transpose-stage C regs -> LDS dst[col][row] (f16). 4 consecutive rows/lane -> ds_write_b64.
__device__ __forceinline__ void stage_ct(const f32x4 acc[4][4], f16* dst, int ld,
                                         int m0, int n0, int l15, int quad) {
#pragma unroll
    for (int mt = 0; mt < 4; ++mt)
#pragma unroll
        for (int nt = 0; nt < 4; ++nt) {
            f16x4 v;
#pragma unroll
            for (int r = 0; r < 4; ++r) v[r] = (f16)acc[mt][nt][r];
            int col = n0 + nt * 16 + l15;
            int row = m0 + mt * 16 + quad * 4;
            *(f16x4*)(dst + (size_t)col * ld + row) = v;
        }
}

// Same but adds the rank-1 bn-correction: dst[col][row] = acc + wsum[col]*g[row].
__device__ __forceinline__ void stage_ct_r1(const f32x4 acc[4][4], f16* dst, int ld,
                                            int m0, int n0, int l15, int quad,
                                            const float* __restrict__ gv,
                                            const float* __restrict__ wv) {
#pragma unroll
    for (int mt = 0; mt < 4; ++mt)
#pragma unroll
        for (int nt = 0; nt < 4; ++nt) {
            int col = n0 + nt * 16 + l15;          // o
            int row0 = m0 + mt * 16 + quad * 4;    // c' base
            float ws = wv[col];
            f16x4 v;
#pragma unroll
            for (int r = 0; r < 4; ++r) v[r] = (f16)(acc[mt][nt][r] + ws * gv[row0 + r]);
            *(f16x4*)(dst + (size_t)col * ld + row0) = v;
        }
}

// Copy a prepacked 128x128 f16 matrix from global into padded LDS region.
__device__ __forceinline__ void stage_w(const f16* __restrict__ g, f16* dst, int tid) {
#pragma unroll
    for (int i = 0; i < 8; ++i) {
        int idx = tid + i * 256;
        int row = idx >> 4, cc = (idx & 15) * 8;
        *(f16x8*)(dst + row * LD1 + cc) = *(const f16x8*)(g + row * 128 + cc);
    }
}

// Prepack weights to f16: slot0=WqT, slot1=WkT, slot4=WoT (slot2=Mt written by prep_mv)
__global__ __launch_bounds__(256) void prep_w(const float* __restrict__ Wq, const float* __restrict__ Wk,
                                              const float* __restrict__ Wo, f16* __restrict__ out) {
    int id = blockIdx.x * 256 + threadIdx.x;  // < 3*16384
    int m = id >> 14;
    int r = (id >> 7) & 127, c = id & 127;
    if (m == 0)      out[id] = (f16)Wq[c * 128 + r];
    else if (m == 1) out[id] = (f16)Wk[c * 128 + r];
    else             out[4 * 16384 + (id & 16383)] = (f16)Wo[c * 128 + r];
}

// Precompute Mt[c'][d] = sum_e Wv[c',e]*Wn[d,e]  (= (Wn*Wv^T)^T, f16, via MFMA),
// and the bias vectors: V = { h1[128] = Wn*bv, g[128] = Wv^T... (sum_e bn[e]Wv[c',e]),
//                             wsum[128] = sum_c Wo[c][o], s0 = bn.bv }
__global__ __launch_bounds__(512) void prep_mv(const float* __restrict__ Wn, const float* __restrict__ Wv,
                                               const float* __restrict__ Wo, const float* __restrict__ bn,
                                               const float* __restrict__ bv,
                                               f16* __restrict__ Wpk, float* __restrict__ Vg) {
    __shared__ f16 As[128 * LD1];
    __shared__ f16 Bs[128 * LD1];
    const int tid = threadIdx.x;
    if (tid < 128) {                  // h1[d]
        float s = 0.f;
        for (int e = 0; e < 128; ++e) s = fmaf(Wn[tid * 128 + e], bv[e], s);
        Vg[tid] = s;
    } else if (tid < 256) {           // g[c']
        int c = tid - 128;
        float s = 0.f;
        for (int e = 0; e < 128; ++e) s = fmaf(bn[e], Wv[c * 128 + e], s);
        Vg[128 + c] = s;
    } else if (tid < 384) {           // wsum[o]
        int o = tid - 256;
        float s = 0.f;
        for (int c = 0; c < 128; ++c) s += Wo[c * 128 + o];
        Vg[256 + o] = s;
    } else if (tid == 384) {          // s0
        float s = 0.f;
        for (int e = 0; e < 128; ++e) s = fmaf(bn[e], bv[e], s);
        Vg[384] = s;
    }
    if (tid < 256) {
#pragma unroll
        for (int i = 0; i < 8; ++i) {
            int idx = tid + i * 256;
            int r = idx >> 4, c = (idx & 15) * 8;
            f16x8 va, vb;
            const float* pa = Wv + r * 128 + c;
            const float* pb = Wn + r * 128 + c;
#pragma unroll
            for (int j = 0; j < 8; ++j) { va[j] = (f16)pa[j]; vb[j] = (f16)pb[j]; }
            *(f16x8*)(As + r * LD1 + c) = va;
            *(f16x8*)(Bs + r * LD1 + c) = vb;
        }
    }
    __syncthreads();
    if (tid < 256) {
        const int lane = tid & 63, wid = tid >> 6;
        const int l15 = lane & 15, quad = lane >> 4;
        const int m0 = (wid >> 1) * 64, n0 = (wid & 1) * 64;
        f32x4 acc[4][4];
        zero_acc(acc);
        gemm_ab(As, LD1, Bs, LD1, 128, m0, n0, l15, quad, acc);   // Mt[c'][d]
        f16* Mt = Wpk + 2 * 16384;
#pragma unroll
        for (int mt = 0; mt < 4; ++mt)
#pragma unroll
            for (int r = 0; r < 4; ++r) {
                int cp = m0 + mt * 16 + quad * 4 + r;
#pragma unroll
                for (int nt = 0; nt < 4; ++nt) {
                    int d = n0 + nt * 16 + l15;
                    Mt[cp * 128 + d] = (f16)acc[mt][nt][r];
                }
            }
    }
}

// T1: x fp32 (B,H,C,W) -> X_t f16 (B,W,C,H)
__global__ __launch_bounds__(256) void t1_k(const float* __restrict__ src, f16* __restrict__ dst) {
    __shared__ float tile[32][33];
    int bx = blockIdx.x;
    const int qt = bx & 3;  bx >>= 2;   // W/32
    const int pt = bx & 7;  bx >>= 3;   // H/32
    const int c  = bx & 127;
    const int b  = bx >> 7;
    const int tx = threadIdx.x & 31, ty = threadIdx.x >> 5;
    size_t sbase = (((size_t)b * HH + pt * 32) * CC + c) * WW + qt * 32;
#pragma unroll
    for (int k = 0; k < 4; ++k) {
        int i = ty + 8 * k;
        tile[i][tx] = src[sbase + (size_t)i * CC * WW + tx];
    }
    __syncthreads();
    size_t dbase = (((size_t)b * WW + qt * 32) * CC + c) * HH + pt * 32;
#pragma unroll
    for (int k = 0; k < 4; ++k) {
        int i = ty + 8 * k;
        dst[dbase + (size_t)i * CC * HH + tx] = (f16)tile[tx][i];
    }
}

// T2: O f16 (B,W,C,H) -> out fp32 (B,H,C,W)
__global__ __launch_bounds__(256) void t2_k(const f16* __restrict__ src, float* __restrict__ dst) {
    __shared__ float tile[32][33];
    int bx = blockIdx.x;
    const int ht = bx & 7;  bx >>= 3;   // H/32
    const int wt = bx & 3;  bx >>= 2;   // W/32
    const int c  = bx & 127;
    const int b  = bx >> 7;
    const int tx = threadIdx.x & 31, ty = threadIdx.x >> 5;
    size_t sbase = (((size_t)b * WW + wt * 32) * CC + c) * HH + ht * 32;
#pragma unroll
    for (int k = 0; k < 4; ++k) {
        int i = ty + 8 * k;          // w offset
        tile[i][tx] = (float)src[sbase + (size_t)i * CC * HH + tx];  // tx = h offset
    }
    __syncthreads();
    size_t dbase = (((size_t)b * HH + ht * 32) * CC + c) * WW + wt * 32;
#pragma unroll
    for (int k = 0; k < 4; ++k) {
        int i = ty + 8 * k;          // h offset
        dst[dbase + (size_t)i * CC * WW + tx] = tile[tx][i];         // tx = w offset
    }
}

// P1 per (b,w): G = X X^T (K=256); S = (Wq^T G Wk + rank-1 bias)/sqrt(W).  S stored f16.
__global__ __launch_bounds__(256, 2) void p1_kernel(const f16* __restrict__ Xt,
                                                    const f16* __restrict__ Wpk,
                                                    const float* __restrict__ Wq_g, const float* __restrict__ bq,
                                                    const float* __restrict__ Wk_g, const float* __restrict__ bk,
                                                    f16* __restrict__ Sout) {
    __shared__ f16 sm[2 * REG];
    __shared__ float rbuf[128], rqb[128], rkb[128];
    const int tid = threadIdx.x;
    const int w = blockIdx.x, b = blockIdx.y;
    const f16* Xg = Xt + (size_t)(b * WW + w) * (CC * HH);
    f16* Xs = sm;          // ld LDX, 128x256
    f16* RA = sm;          // ld LD1
    f16* RB = sm + REG;    // ld LD1

#pragma unroll
    for (int i = 0; i < 16; ++i) {
        int g = tid + i * 256;
        int row = g >> 5, cc = (g & 31) * 8;
        *(f16x8*)(Xs + row * LDX + cc) = *(const f16x8*)(Xg + row * 256 + cc);
    }
    __syncthreads();

    const int lane = tid & 63, wid = tid >> 6;
    const int l15 = lane & 15, quad = lane >> 4;
    const int m0 = (wid >> 1) * 64, n0 = (wid & 1) * 64;

    // r[c] = sum_h X[c,h]
    if (tid < 128) {
        float s = 0.f;
        for (int hc = 0; hc < 32; ++hc) {
            f16x8 v = *(const f16x8*)(Xs + tid * LDX + hc * 8);
#pragma unroll
            for (int j = 0; j < 8; ++j) s += (float)v[j];
        }
        rbuf[tid] = s;
    }

    f32x4 acc[4][4];
    zero_acc(acc);
    gemm_ab(Xs, LDX, Xs, LDX, 256, m0, n0, l15, quad, acc);  // G[c][c2]
    __syncthreads();

    stage_ct(acc, RA, LD1, m0, n0, l15, quad);  // Gs[c2][c] (= G, symmetric)
    stage_w(Wpk + 0 * 16384, RB, tid);          // WqT[dq][c]
    if (tid < 128) {                            // rq = Wq^T r
        float s = 0.f;
        for (int c = 0; c < 128; ++c) s = fmaf(Wq_g[c * 128 + tid], rbuf[c], s);
        rqb[tid] = s;
    } else {                                    // rk = Wk^T r
        int d = tid - 128;
        float s = 0.f;
        for (int c = 0; c < 128; ++c) s = fmaf(Wk_g[c * 128 + d], rbuf[c], s);
        rkb[d] = s;
    }
    __syncthreads();

    zero_acc(acc);
    gemm_ab(RA, LD1, RB, LD1, 128, m0, n0, l15, quad, acc);  // Tt[c2][dq]
    __syncthreads();
    stage_ct(acc, RA, LD1, m0, n0, l15, quad);  // Ts[dq][c2]
    stage_w(Wpk + 1 * 16384, RB, tid);          // WkT[dk][c2]
    __syncthreads();

    zero_acc(acc);
    gemm_ab(RA, LD1, RB, LD1, 128, m0, n0, l15, quad, acc);  // S[dq][dk]

    const float inv_scale = 0.08838834764831845f;  // 1/sqrt(128)
    f16* Sg = Sout + (size_t)(b * WW + w) * (CC * CC);
#pragma unroll
    for (int mt = 0; mt < 4; ++mt)
#pragma unroll
        for (int r = 0; r < 4; ++r) {
            int dq = m0 + mt * 16 + quad * 4 + r;
            float q1 = bq[dq], q2 = rqb[dq];
#pragma unroll
            for (int nt = 0; nt < 4; ++nt) {
                int dk = n0 + nt * 16 + l15;
                float kb = bk[dk], kr = rkb[dk];
                Sg[dq * 128 + dk] = (f16)((acc[mt][nt][r] + q2 * kb + q1 * kr + 256.f * q1 * kb) * inv_scale);
            }
        }
}

// P2: online softmax stats over w (f16 S in). z[b,c,d] = max + log(sum exp(. - max)). 2 elems/thread.
__global__ __launch_bounds__(256) void p2_kernel(const f16* __restrict__ S,
                                                 float* __restrict__ z) {
    int i = (blockIdx.x * 256 + threadIdx.x) * 2;   // i < BB*CC*CC
    int b = i >> 14, cd = i & 16383;
    const f16* p = S + (size_t)b * WW * CC * CC + cd;
    float m0v = -1e30f, l0 = 0.f, m1v = -1e30f, l1 = 0.f;
    for (int w = 0; w < WW; ++w) {
        f16x2 sv = *(const f16x2*)(p + (size_t)w * CC * CC);
        float s0 = (float)sv[0], s1 = (float)sv[1];
        if (s0 > m0v) { l0 = fmaf(l0, __expf(m0v - s0), 1.f); m0v = s0; }
        else          { l0 += __expf(s0 - m0v); }
        if (s1 > m1v) { l1 = fmaf(l1, __expf(m1v - s1), 1.f); m1v = s1; }
        else          { l1 += __expf(s1 - m1v); }
    }
    z[i]     = m0v + __logf(l0);
    z[i + 1] = m1v + __logf(l1);
}

// P3 per (b,w): A=exp(S-z); T = A*M; P^T = T^T*Wo (+rank-1); O = P*X + u*1^T
__global__ __launch_bounds__(256, 2) void p3_kernel(f16* __restrict__ XtO,
                                                    const f16* __restrict__ Sin, const float* __restrict__ Zin,
                                                    const f16* __restrict__ Wpk,
                                                    const float* __restrict__ Vg,
                                                    const float* __restrict__ bo_g) {
    __shared__ f16 sm[2 * REG];
    __shared__ float t1b[128], ub[128], gb[128], wb[128];
    const int tid = threadIdx.x;
    const int w = blockIdx.x, b = blockIdx.y;
    const f16* Sg = Sin + (size_t)(b * WW + w) * (CC * CC);
    const float* Zb = Zin + (size_t)b * (CC * CC);
    f16* Xg = XtO + (size_t)(b * WW + w) * (CC * HH);
    f16* R0 = sm;
    f16* R1 = sm + REG;

    if (tid < 128) { gb[tid] = Vg[128 + tid]; wb[tid] = Vg[256 + tid]; }

    // As[c][d] = exp(S - z) -> R0
#pragma unroll
    for (int i = 0; i < 16; ++i) {
        int g = tid + i * 256;
        int c = g >> 5, d4 = (g & 31) * 4;
        f16x4 s4 = *(const f16x4*)(Sg + c * 128 + d4);
        float4 z4 = *(const float4*)(Zb + c * 128 + d4);
        f16x4 e;
        e[0] = (f16)__expf((float)s4[0] - z4.x);
        e[1] = (f16)__expf((float)s4[1] - z4.y);
        e[2] = (f16)__expf((float)s4[2] - z4.z);
        e[3] = (f16)__expf((float)s4[3] - z4.w);
        *(f16x4*)(R0 + c * LD1 + d4) = e;
    }
    stage_w(Wpk + 2 * 16384, R1, tid);   // Mt[c'][d]
    __syncthreads();                     // B1

    const int lane = tid & 63, wid = tid >> 6;
    const int l15 = lane & 15, quad = lane >> 4;
    const int m0 = (wid >> 1) * 64, n0 = (wid & 1) * 64;

    if (tid < 128) {                     // t1[c] = sum_d A[c][d]*h1[d] + s0
        float s = Vg[384];
        for (int d = 0; d < 128; ++d) s = fmaf((float)R0[tid * LD1 + d], Vg[d], s);
        t1b[tid] = s;
    }

    f32x4 acc[4][4];
    zero_acc(acc);
    gemm_ab(R0, LD1, R1, LD1, 128, m0, n0, l15, quad, acc);  // T[c][c'] = sum_d A[c,d] M[d,c']
    __syncthreads();                     // B2
    stage_ct(acc, R0, LD1, m0, n0, l15, quad);               // Ts[c'][c]
    stage_w(Wpk + 4 * 16384, R1, tid);                       // WoT[o][c]
    __syncthreads();                     // B3
    if (tid < 128) {                     // u[o] = sum_c WoT[o][c]*t1[c] + bo[o]
        float s = 0.f;
        for (int c = 0; c < 128; ++c) s = fmaf((float)R1[tid * LD1 + c], t1b[c], s);
        ub[tid] = s + bo_g[tid];
    }
    zero_acc(acc);
    gemm_ab(R0, LD1, R1, LD1, 128, m0, n0, l15, quad, acc);  // Pt[c'][o]
    __syncthreads();                     // B4
    stage_ct_r1(acc, R1, LD1, m0, n0, l15, quad, gb, wb);    // Ps[o][c'] += wsum[o]*g[c']
    // X half0 (h in [0,128)) -> R0 subtiled for tr reads
#pragma unroll
    for (int i = 0; i < 16; ++i) {
        int g = tid + i * 256;
        int c2 = g >> 5, cc = (g & 31) * 4;
        int off = ((c2 >> 2) * 8 + (cc >> 4)) * 68 + (c2 & 3) * 16 + (cc & 12);
        *(f16x4*)(R0 + off) = *(const f16x4*)(Xg + c2 * 256 + cc);
    }
    __syncthreads();                     // B5
    zero_acc(acc);
    gemm_a_btr(R1, LD1, R0, m0, n0, l15, quad, acc);         // O[o][0:128]
#pragma unroll
    for (int mt = 0; mt < 4; ++mt)
#pragma unroll
        for (int r = 0; r < 4; ++r) {
            int o = m0 + mt * 16 + quad * 4 + r;
            float u = ub[o];
#pragma unroll
            for (int nt = 0; nt < 4; ++nt) {
                int h = n0 + nt * 16 + l15;
                Xg[o * 256 + h] = (f16)(acc[mt][nt][r] + u);
            }
        }
    __syncthreads();                     // B6
    // X half1 (h in [128,256)) -> R0 (disjoint from O half0 writes)
#pragma unroll
    for (int i = 0; i < 16; ++i) {
        int g = tid + i * 256;
        int c2 = g >> 5, cc = (g & 31) * 4;
        int off = ((c2 >> 2) * 8 + (cc >> 4)) * 68 + (c2 & 3) * 16 + (cc & 12);
        *(f16x4*)(R0 + off) = *(const f16x4*)(Xg + c2 * 256 + 128 + cc);
    }
    __syncthreads();                     // B7
    zero_acc(acc);
    gemm_a_btr(R1, LD1, R0, m0, n0, l15, quad, acc);         // O[o][128:256]
#pragma unroll
    for (int mt = 0; mt < 4; ++mt)
#pragma unroll
        for (int r = 0; r < 4; ++r) {
            int o = m0 + mt * 16 + quad * 4 + r;
            float u = ub[o];
#pragma unroll
            for (int nt = 0; nt < 4; ++nt) {
                int h = n0 + nt * 16 + l15;
                Xg[o * 256 + 128 + h] = (f16)(acc[mt][nt][r] + u);
            }
        }
}

extern "C" void kernel_launch(void* const* d_in, const int* in_sizes, int n_in,
                              void* d_out, int out_size, void* d_ws, size_t ws_size,
                              hipStream_t stream) {
    const float* x  = (const float*)d_in[0];
    const float* Wq = (const float*)d_in[1];
    const float* bq = (const float*)d_in[2];
    const float* Wk = (const float*)d_in[3];
    const float* bk = (const float*)d_in[4];
    const float* Wv = (const float*)d_in[5];
    const float* bv = (const float*)d_in[6];
    const float* Wn = (const float*)d_in[7];
    const float* bn = (const float*)d_in[8];
    const float* Wo = (const float*)d_in[9];
    const float* bo = (const float*)d_in[10];
    float* out = (float*)d_out;

    f16*   wsX = (f16*)d_ws;                                        // (B,W,C,H) f16: 134217728 B
    f16*   wsS = (f16*)((char*)d_ws + 134217728);                   // scores f16: 67108864 B
    float* wsV = (float*)((char*)d_ws + 134217728 + 67108864);      // h1/g/wsum/s0: 2KB
    float* wsZ = (float*)((char*)d_ws + 268435456);                 // softmax z: 1 MB
    f16*   wsW = (f16*)((char*)d_ws + 268435456 + 1048576);         // packed weights: 160 KB

    prep_w<<<192, 256, 0, stream>>>(Wq, Wk, Wo, wsW);
    prep_mv<<<1, 512, 0, stream>>>(Wn, Wv, Wo, bn, bv, wsW, wsV);
    t1_k<<<BB * CC * 8 * 4, 256, 0, stream>>>(x, wsX);
    p1_kernel<<<dim3(WW, BB), 256, 0, stream>>>(wsX, wsW, Wq, bq, Wk, bk, wsS);
    p2_kernel<<<(BB * CC * CC) / 512, 256, 0, stream>>>(wsS, wsZ);
    p3_kernel<<<dim3(WW, BB), 256, 0, stream>>>(wsX, wsS, wsZ, wsW, wsV, bo);
    t2_k<<<BB * CC * 4 * 8, 256, 0, stream>>>(wsX, out);
}

// Round 3
// 691.219 us; speedup vs baseline: 1.0604x; 1.0604x over previous
//
#include <hip/hip_runtime.h>
#include <cstddef>

// Problem constants
#define BB 16
#define HH 256
#define CC 128
#define WW 128

typedef _Float16 f16;
typedef _Float16 f16x8 __attribute__((ext_vector_type(8)));
typedef _Float16 f16x4 __attribute__((ext_vector_type(4)));
typedef _Float16 f16x2 __attribute__((ext_vector_type(2)));
typedef float f32x4 __attribute__((ext_vector_type(4)));

#define LD1 136   // padded ld (f16) for K=128 operands: 272B stride -> 2-way max on b128 frag reads
#define LDX 264   // padded ld (f16) for K=256 X operand in P1
#define REG 17920 // f16 elems per LDS region

__device__ __forceinline__ void zero_acc(f32x4 acc[4][4]) {
#pragma unroll
    for (int i = 0; i < 4; ++i)
#pragma unroll
        for (int j = 0; j < 4; ++j) acc[i][j] = (f32x4){0.f, 0.f, 0.f, 0.f};
}

// C[128x128] += A(128xK, lds) * B^T-layout(Bt[n][k], lds). Wave covers 64x64 (4x4 tiles 16x16).
__device__ __forceinline__ void gemm_ab(const f16* __restrict__ A, int lda,
                                        const f16* __restrict__ B, int ldb,
                                        int K, int m0, int n0, int l15, int quad,
                                        f32x4 acc[4][4]) {
    for (int kc = 0; kc < K; kc += 32) {
        f16x8 af[4], bf[4];
        const f16* ap = A + (size_t)(m0 + l15) * lda + kc + quad * 8;
        const f16* bp = B + (size_t)(n0 + l15) * ldb + kc + quad * 8;
#pragma unroll
        for (int t = 0; t < 4; ++t) {
            af[t] = *(const f16x8*)(ap + t * 16 * lda);
            bf[t] = *(const f16x8*)(bp + t * 16 * ldb);
        }
#pragma unroll
        for (int mt = 0; mt < 4; ++mt)
#pragma unroll
            for (int nt = 0; nt < 4; ++nt)
                acc[mt][nt] = __builtin_amdgcn_mfma_f32_16x16x32_f16(af[mt], bf[nt], acc[mt][nt], 0, 0, 0);
    }
}

// C[128x128] += A(128x128, lds, ld=lda) * X(128x128) where X is staged SUBTILED in LDS:
// subtile (c2q=c2>>2, hq=h>>4) at f16 offset (c2q*8+hq)*68, elem (c2&3, h&15) at +(c2&3)*16+(h&15).
// B fragments via ds_read_b64_tr_b16: lane l15 receives column l15, rows j of the 4x16 subtile.
__device__ __forceinline__ void gemm_a_btr(const f16* __restrict__ A, int lda,
                                           const f16* __restrict__ XS,
                                           int m0, int n0, int l15, int quad,
                                           f32x4 acc[4][4]) {
    const unsigned xb = (unsigned)(size_t)XS;   // LDS byte address (low 32 bits of flat)
    for (int kc = 0; kc < 128; kc += 32) {
        f16x8 af[4];
        const f16* ap = A + (size_t)(m0 + l15) * lda + kc + quad * 8;
#pragma unroll
        for (int t = 0; t < 4; ++t) af[t] = *(const f16x8*)(ap + t * 16 * lda);
        int i0 = (kc >> 2) + 2 * quad;          // c2q for tau=0
        f16x4 blo[4], bhi[4];
#pragma unroll
        for (int nt = 0; nt < 4; ++nt) {
            unsigned idx0 = (unsigned)(i0 * 8 + (n0 >> 4) + nt);
            unsigned a0 = xb + (idx0 * 68u + (unsigned)l15 * 4u) * 2u;
            unsigned a1 = a0 + 8u * 68u * 2u;   // tau=1: c2q+1 -> idx+8
            asm volatile("ds_read_b64_tr_b16 %0, %1" : "=v"(blo[nt]) : "v"(a0));
            asm volatile("ds_read_b64_tr_b16 %0, %1" : "=v"(bhi[nt]) : "v"(a1));
        }
        asm volatile("s_waitcnt lgkmcnt(0)" ::: "memory");
        __builtin_amdgcn_sched_barrier(0);
#pragma unroll
        for (int nt = 0; nt < 4; ++nt) {
            f16x8 bv = __builtin_shufflevector(blo[nt], bhi[nt], 0, 1, 2, 3, 4, 5, 6, 7);
#pragma unroll
            for (int mt = 0; mt < 4; ++mt)
                acc[mt][nt] = __builtin_amdgcn_mfma_f32_16x16x32_f16(af[mt], bv, acc[mt][nt], 0, 0, 0);
        }
    }
}

// Transpose-stage C regs -> LDS dst[col][row] (f16). 4 consecutive rows/lane -> ds_write_b64.
__device__ __forceinline__ void stage_ct(const f32x4 acc[4][4], f16* dst, int ld,
                                         int m0, int n0, int l15, int quad) {
#pragma unroll
    for (int mt = 0; mt < 4; ++mt)
#pragma unroll
        for (int nt = 0; nt < 4; ++nt) {
            f16x4 v;
#pragma unroll
            for (int r = 0; r < 4; ++r) v[r] = (f16)acc[mt][nt][r];
            int col = n0 + nt * 16 + l15;
            int row = m0 + mt * 16 + quad * 4;
            *(f16x4*)(dst + (size_t)col * ld + row) = v;
        }
}

// Mirror stage (for symmetric G): dst[row][col] = acc (scalar stores, conflict-free banks).
__device__ __forceinline__ void stage_c_mirror(const f32x4 acc[4][4], f16* dst, int ld,
                                               int m0, int n0, int l15, int quad) {
#pragma unroll
    for (int mt = 0; mt < 4; ++mt)
#pragma unroll
        for (int r = 0; r < 4; ++r) {
            int row = m0 + mt * 16 + quad * 4 + r;
#pragma unroll
            for (int nt = 0; nt < 4; ++nt)
                dst[(size_t)row * ld + n0 + nt * 16 + l15] = (f16)acc[mt][nt][r];
        }
}

// Same as stage_ct but adds rank-1 bn-correction: dst[col][row] = acc + wsum[col]*g[row].
__device__ __forceinline__ void stage_ct_r1(const f32x4 acc[4][4], f16* dst, int ld,
                                            int m0, int n0, int l15, int quad,
                                            const float* __restrict__ gv,
                                            const float* __restrict__ wv) {
#pragma unroll
    for (int mt = 0; mt < 4; ++mt)
#pragma unroll
        for (int nt = 0; nt < 4; ++nt) {
            int col = n0 + nt * 16 + l15;          // o
            int row0 = m0 + mt * 16 + quad * 4;    // c' base
            float ws = wv[col];
            f16x4 v;
#pragma unroll
            for (int r = 0; r < 4; ++r) v[r] = (f16)(acc[mt][nt][r] + ws * gv[row0 + r]);
            *(f16x4*)(dst + (size_t)col * ld + row0) = v;
        }
}

// Copy a prepacked 128x128 f16 matrix from global into padded LDS region.
__device__ __forceinline__ void stage_w(const f16* __restrict__ g, f16* dst, int tid) {
#pragma unroll
    for (int i = 0; i < 8; ++i) {
        int idx = tid + i * 256;
        int row = idx >> 4, cc = (idx & 15) * 8;
        *(f16x8*)(dst + row * LD1 + cc) = *(const f16x8*)(g + row * 128 + cc);
    }
}

// T14 issue-early helpers: load a 128x128 f16 matrix into 32 VGPRs, write to LDS later.
__device__ __forceinline__ void load_w_reg(const f16* __restrict__ g, f16x8 wr[8], int tid) {
#pragma unroll
    for (int i = 0; i < 8; ++i) {
        int idx = tid + i * 256;
        wr[i] = *(const f16x8*)(g + (idx >> 4) * 128 + (idx & 15) * 8);
    }
}
__device__ __forceinline__ void stage_w_from_reg(const f16x8 wr[8], f16* dst, int tid) {
#pragma unroll
    for (int i = 0; i < 8; ++i) {
        int idx = tid + i * 256;
        *(f16x8*)(dst + (idx >> 4) * LD1 + (idx & 15) * 8) = wr[i];
    }
}
// X-half (128 rows x 128 h, row stride 256) into regs; later write subtiled for tr-reads.
__device__ __forceinline__ void load_x_reg(const f16* __restrict__ g, f16x8 wr[8], int tid) {
#pragma unroll
    for (int i = 0; i < 8; ++i) {
        int idx = tid + i * 256;
        wr[i] = *(const f16x8*)(g + (idx >> 4) * 256 + (idx & 15) * 8);
    }
}
__device__ __forceinline__ void stage_x_from_reg(const f16x8 wr[8], f16* dst, int tid) {
#pragma unroll
    for (int i = 0; i < 8; ++i) {
        int idx = tid + i * 256;
        int c2 = idx >> 4, cc = (idx & 15) * 8;
        int off = ((c2 >> 2) * 8 + (cc >> 4)) * 68 + (c2 & 3) * 16 + (cc & 15);
        f16x4 lo, hi;
#pragma unroll
        for (int j = 0; j < 4; ++j) { lo[j] = wr[i][j]; hi[j] = wr[i][4 + j]; }
        *(f16x4*)(dst + off) = lo;
        *(f16x4*)(dst + off + 4) = hi;
    }
}

// Prepack weights to f16: slot0=WqT, slot1=WkT, slot4=WoT (slot2=Mt written by prep_mv)
__global__ __launch_bounds__(256) void prep_w(const float* __restrict__ Wq, const float* __restrict__ Wk,
                                              const float* __restrict__ Wo, f16* __restrict__ out) {
    int id = blockIdx.x * 256 + threadIdx.x;  // < 3*16384
    int m = id >> 14;
    int r = (id >> 7) & 127, c = id & 127;
    if (m == 0)      out[id] = (f16)Wq[c * 128 + r];
    else if (m == 1) out[id] = (f16)Wk[c * 128 + r];
    else             out[4 * 16384 + (id & 16383)] = (f16)Wo[c * 128 + r];
}

// Precompute Mt[c'][d] = sum_e Wv[c',e]*Wn[d,e] (f16, via MFMA), and bias vectors:
// V = { h1[128]=Wn*bv, g[128]=sum_e bn[e]Wv[c',e], wsum[128]=sum_c Wo[c][o], s0=bn.bv }
__global__ __launch_bounds__(512) void prep_mv(const float* __restrict__ Wn, const float* __restrict__ Wv,
                                               const float* __restrict__ Wo, const float* __restrict__ bn,
                                               const float* __restrict__ bv,
                                               f16* __restrict__ Wpk, float* __restrict__ Vg) {
    __shared__ f16 As[128 * LD1];
    __shared__ f16 Bs[128 * LD1];
    const int tid = threadIdx.x;
    if (tid < 128) {                  // h1[d]
        float s = 0.f;
        for (int e = 0; e < 128; ++e) s = fmaf(Wn[tid * 128 + e], bv[e], s);
        Vg[tid] = s;
    } else if (tid < 256) {           // g[c']
        int c = tid - 128;
        float s = 0.f;
        for (int e = 0; e < 128; ++e) s = fmaf(bn[e], Wv[c * 128 + e], s);
        Vg[128 + c] = s;
    } else if (tid < 384) {           // wsum[o]
        int o = tid - 256;
        float s = 0.f;
        for (int c = 0; c < 128; ++c) s += Wo[c * 128 + o];
        Vg[256 + o] = s;
    } else if (tid == 384) {          // s0
        float s = 0.f;
        for (int e = 0; e < 128; ++e) s = fmaf(bn[e], bv[e], s);
        Vg[384] = s;
    }
    if (tid < 256) {
#pragma unroll
        for (int i = 0; i < 8; ++i) {
            int idx = tid + i * 256;
            int r = idx >> 4, c = (idx & 15) * 8;
            f16x8 va, vb;
            const float* pa = Wv + r * 128 + c;
            const float* pb = Wn + r * 128 + c;
#pragma unroll
            for (int j = 0; j < 8; ++j) { va[j] = (f16)pa[j]; vb[j] = (f16)pb[j]; }
            *(f16x8*)(As + r * LD1 + c) = va;
            *(f16x8*)(Bs + r * LD1 + c) = vb;
        }
    }
    __syncthreads();
    if (tid < 256) {
        const int lane = tid & 63, wid = tid >> 6;
        const int l15 = lane & 15, quad = lane >> 4;
        const int m0 = (wid >> 1) * 64, n0 = (wid & 1) * 64;
        f32x4 acc[4][4];
        zero_acc(acc);
        gemm_ab(As, LD1, Bs, LD1, 128, m0, n0, l15, quad, acc);   // Mt[c'][d]
        f16* Mt = Wpk + 2 * 16384;
#pragma unroll
        for (int mt = 0; mt < 4; ++mt)
#pragma unroll
            for (int r = 0; r < 4; ++r) {
                int cp = m0 + mt * 16 + quad * 4 + r;
#pragma unroll
                for (int nt = 0; nt < 4; ++nt) {
                    int d = n0 + nt * 16 + l15;
                    Mt[cp * 128 + d] = (f16)acc[mt][nt][r];
                }
            }
    }
}

// T1: x fp32 (B,H,C,W) -> X_t f16 (B,W,C,H). 64x64 tile, float4 loads / f16x8 stores.
__global__ __launch_bounds__(256) void t1_k(const float* __restrict__ src, f16* __restrict__ dst) {
    __shared__ float tile[64][68];
    int bx = blockIdx.x;
    const int pw = bx & 1;  bx >>= 1;   // W/64
    const int ph = bx & 3;  bx >>= 2;   // H/64
    const int c  = bx & 127;
    const int b  = bx >> 7;
    const int tid = threadIdx.x;
    const int h0 = ph * 64, w0 = pw * 64;
    {
        const int r = tid >> 4, c4 = (tid & 15) * 4;
        size_t base = (((size_t)b * HH + h0 + r) * CC + c) * WW + w0 + c4;
#pragma unroll
        for (int k = 0; k < 4; ++k) {
            float4 v = *(const float4*)(src + base + (size_t)(16 * k) * CC * WW);
            *(float4*)&tile[r + 16 * k][c4] = v;
        }
    }
    __syncthreads();
    {
        const int rw = tid >> 3, h8 = (tid & 7) * 8;
        size_t dbase = (((size_t)b * WW + w0 + rw) * CC + c) * HH + h0 + h8;
#pragma unroll
        for (int k = 0; k < 2; ++k) {
            f16x8 v;
#pragma unroll
            for (int j = 0; j < 8; ++j) v[j] = (f16)tile[h8 + j][rw + 32 * k];
            *(f16x8*)(dst + dbase + (size_t)(32 * k) * CC * HH) = v;
        }
    }
}

// T2: O' f16 (B,W,H,C) -> out fp32 (B,H,C,W). 64(w)x64(c) tile at fixed (b,h).
__global__ __launch_bounds__(256) void t2_k(const f16* __restrict__ src, float* __restrict__ dst) {
    __shared__ float tile[64][68];   // [w][c]
    int bx = blockIdx.x;
    const int ct = bx & 1;  bx >>= 1;   // C/64
    const int wt = bx & 1;  bx >>= 1;   // W/64
    const int h  = bx & 255;
    const int b  = bx >> 8;
    const int tid = threadIdx.x;
    const int c0 = ct * 64, w0 = wt * 64;
    {
        const int r = tid >> 3, c8 = (tid & 7) * 8;
#pragma unroll
        for (int k = 0; k < 2; ++k) {
            int wr = r + 32 * k;
            f16x8 v = *(const f16x8*)(src + (((size_t)b * WW + w0 + wr) * HH + h) * CC + c0 + c8);
#pragma unroll
            for (int j = 0; j < 8; ++j) tile[wr][c8 + j] = (float)v[j];
        }
    }
    __syncthreads();
    {
        const int rc = tid >> 4, w4 = (tid & 15) * 4;
#pragma unroll
        for (int k = 0; k < 4; ++k) {
            int cr = rc + 16 * k;
            float4 o;
            o.x = tile[w4 + 0][cr]; o.y = tile[w4 + 1][cr];
            o.z = tile[w4 + 2][cr]; o.w = tile[w4 + 3][cr];
            *(float4*)(dst + (((size_t)b * HH + h) * CC + c0 + cr) * WW + w0 + w4) = o;
        }
    }
}

// P1 per (b,w): G = X X^T (K=256, symmetric); S = (Wq^T G Wk + rank-1 bias)/sqrt(W). S f16.
__global__ __launch_bounds__(256, 2) void p1_kernel(const f16* __restrict__ Xt,
                                                    const f16* __restrict__ Wpk,
                                                    const float* __restrict__ Wq_g, const float* __restrict__ bq,
                                                    const float* __restrict__ Wk_g, const float* __restrict__ bk,
                                                    f16* __restrict__ Sout) {
    __shared__ f16 sm[2 * REG];
    __shared__ float rbuf[128], rqb[128], rkb[128];
    const int tid = threadIdx.x;
    const int w = blockIdx.x, b = blockIdx.y;
    const f16* Xg = Xt + (size_t)(b * WW + w) * (CC * HH);
    f16* Xs = sm;          // ld LDX, 128x256
    f16* RA = sm;          // ld LD1
    f16* RB = sm + REG;    // ld LD1

    f16x8 wkreg[8];
    load_w_reg(Wpk + 1 * 16384, wkreg, tid);   // T14: WkT loads issued at start

#pragma unroll
    for (int i = 0; i < 16; ++i) {
        int g = tid + i * 256;
        int row = g >> 5, cc = (g & 31) * 8;
        *(f16x8*)(Xs + row * LDX + cc) = *(const f16x8*)(Xg + row * 256 + cc);
    }
    __syncthreads();

    const int lane = tid & 63, wid = tid >> 6;
    const int l15 = lane & 15, quad = lane >> 4;
    const int m0 = (wid >> 1) * 64, n0 = (wid & 1) * 64;

    f32x4 acc[4][4];
    if (wid != 2) {
        zero_acc(acc);
        gemm_ab(Xs, LDX, Xs, LDX, 256, m0, n0, l15, quad, acc);  // G tiles (0,0),(0,64),(64,64)
    } else {
        // wave 2: r[c] = sum_h X[c,h] (its G tile is wave 1's transpose)
#pragma unroll
        for (int hf = 0; hf < 2; ++hf) {
            int c = lane + 64 * hf;
            float s = 0.f;
            for (int hc = 0; hc < 32; ++hc) {
                f16x8 v = *(const f16x8*)(Xs + (size_t)c * LDX + hc * 8);
#pragma unroll
                for (int j = 0; j < 8; ++j) s += (float)v[j];
            }
            rbuf[c] = s;
        }
    }
    __syncthreads();

    if (wid != 2) stage_ct(acc, RA, LD1, m0, n0, l15, quad);      // Gs[c2][c]
    if (wid == 1) stage_c_mirror(acc, RA, LD1, m0, n0, l15, quad); // covers wave2's region
    stage_w(Wpk + 0 * 16384, RB, tid);          // WqT[dq][c]
    if (tid < 128) {                            // rq = Wq^T r
        float s = 0.f;
        for (int c = 0; c < 128; ++c) s = fmaf(Wq_g[c * 128 + tid], rbuf[c], s);
        rqb[tid] = s;
    } else {                                    // rk = Wk^T r
        int d = tid - 128;
        float s = 0.f;
        for (int c = 0; c < 128; ++c) s = fmaf(Wk_g[c * 128 + d], rbuf[c], s);
        rkb[d] = s;
    }
    __syncthreads();

    zero_acc(acc);
    gemm_ab(RA, LD1, RB, LD1, 128, m0, n0, l15, quad, acc);  // Tt[c2][dq]
    __syncthreads();
    stage_ct(acc, RA, LD1, m0, n0, l15, quad);  // Ts[dq][c2]
    stage_w_from_reg(wkreg, RB, tid);           // WkT[dk][c2] (from regs, no global latency)
    __syncthreads();

    zero_acc(acc);
    gemm_ab(RA, LD1, RB, LD1, 128, m0, n0, l15, quad, acc);  // S[dq][dk]

    const float inv_scale = 0.08838834764831845f;  // 1/sqrt(128)
    f16* Sg = Sout + (size_t)(b * WW + w) * (CC * CC);
#pragma unroll
    for (int mt = 0; mt < 4; ++mt)
#pragma unroll
        for (int r = 0; r < 4; ++r) {
            int dq = m0 + mt * 16 + quad * 4 + r;
            float q1 = bq[dq], q2 = rqb[dq];
#pragma unroll
            for (int nt = 0; nt < 4; ++nt) {
                int dk = n0 + nt * 16 + l15;
                float kb = bk[dk], kr = rkb[dk];
                Sg[dq * 128 + dk] = (f16)((acc[mt][nt][r] + q2 * kb + q1 * kr + 256.f * q1 * kb) * inv_scale);
            }
        }
}

// P2: online softmax stats over w (f16 S in). Branchless, w-unrolled x4, 2 elems/thread.
__global__ __launch_bounds__(256) void p2_kernel(const f16* __restrict__ S,
                                                 float* __restrict__ z) {
    int i = (blockIdx.x * 256 + threadIdx.x) * 2;   // i < BB*CC*CC
    int b = i >> 14, cd = i & 16383;
    const f16* p = S + (size_t)b * WW * CC * CC + cd;
    float m0v = -1e30f, l0 = 0.f, m1v = -1e30f, l1 = 0.f;
    for (int w = 0; w < WW; w += 4) {
        f16x2 v0 = *(const f16x2*)(p + (size_t)(w + 0) * CC * CC);
        f16x2 v1 = *(const f16x2*)(p + (size_t)(w + 1) * CC * CC);
        f16x2 v2 = *(const f16x2*)(p + (size_t)(w + 2) * CC * CC);
        f16x2 v3 = *(const f16x2*)(p + (size_t)(w + 3) * CC * CC);
#pragma unroll
        for (int j = 0; j < 4; ++j) {
            f16x2 v = (j == 0) ? v0 : (j == 1) ? v1 : (j == 2) ? v2 : v3;
            float s0 = (float)v[0], s1 = (float)v[1];
            float n0 = fmaxf(m0v, s0), n1 = fmaxf(m1v, s1);
            l0 = fmaf(l0, __expf(m0v - n0), __expf(s0 - n0)); m0v = n0;
            l1 = fmaf(l1, __expf(m1v - n1), __expf(s1 - n1)); m1v = n1;
        }
    }
    z[i]     = m0v + __logf(l0);
    z[i + 1] = m1v + __logf(l1);
}

// P3 per (b,w): A=exp(S-z); T = A*M; P^T = T^T*Wo (+rank-1); O = P*X + u*1^T.
// O written as O'(B,W,H,C) with f16x4 stores (t2 adapted).
__global__ __launch_bounds__(256, 2) void p3_kernel(f16* __restrict__ XtO,
                                                    const f16* __restrict__ Sin, const float* __restrict__ Zin,
                                                    const f16* __restrict__ Wpk,
                                                    const float* __restrict__ Vg,
                                                    const float* __restrict__ bo_g) {
    __shared__ f16 sm[2 * REG];
    __shared__ float t1b[128], ub[128], gb[128], wb[128];
    const int tid = threadIdx.x;
    const int w = blockIdx.x, b = blockIdx.y;
    const f16* Sg = Sin + (size_t)(b * WW + w) * (CC * CC);
    const float* Zb = Zin + (size_t)b * (CC * CC);
    f16* Xg = XtO + (size_t)(b * WW + w) * (CC * HH);
    f16* R0 = sm;
    f16* R1 = sm + REG;

    f16x8 wreg[8];
    load_w_reg(Wpk + 4 * 16384, wreg, tid);     // T14: WoT loads issued at start

    if (tid < 128) { gb[tid] = Vg[128 + tid]; wb[tid] = Vg[256 + tid]; }

    // As[c][d] = exp(S - z) -> R0 (8-wide)
#pragma unroll
    for (int i = 0; i < 8; ++i) {
        int g = tid + i * 256;
        int c = g >> 4, d8 = (g & 15) * 8;
        f16x8 s8 = *(const f16x8*)(Sg + c * 128 + d8);
        float4 za = *(const float4*)(Zb + c * 128 + d8);
        float4 zc = *(const float4*)(Zb + c * 128 + d8 + 4);
        f16x8 e;
        e[0] = (f16)__expf((float)s8[0] - za.x);
        e[1] = (f16)__expf((float)s8[1] - za.y);
        e[2] = (f16)__expf((float)s8[2] - za.z);
        e[3] = (f16)__expf((float)s8[3] - za.w);
        e[4] = (f16)__expf((float)s8[4] - zc.x);
        e[5] = (f16)__expf((float)s8[5] - zc.y);
        e[6] = (f16)__expf((float)s8[6] - zc.z);
        e[7] = (f16)__expf((float)s8[7] - zc.w);
        *(f16x8*)(R0 + c * LD1 + d8) = e;
    }
    stage_w(Wpk + 2 * 16384, R1, tid);   // Mt[c'][d]
    __syncthreads();                     // B1

    const int lane = tid & 63, wid = tid >> 6;
    const int l15 = lane & 15, quad = lane >> 4;
    const int m0 = (wid >> 1) * 64, n0 = (wid & 1) * 64;

    if (tid < 128) {                     // t1[c] = sum_d A[c][d]*h1[d] + s0
        float s = Vg[384];
        for (int d = 0; d < 128; ++d) s = fmaf((float)R0[tid * LD1 + d], Vg[d], s);
        t1b[tid] = s;
    }

    f32x4 acc[4][4];
    zero_acc(acc);
    gemm_ab(R0, LD1, R1, LD1, 128, m0, n0, l15, quad, acc);  // T[c][c']
    __syncthreads();                     // B2
    stage_ct(acc, R0, LD1, m0, n0, l15, quad);               // Ts[c'][c]
    stage_w_from_reg(wreg, R1, tid);                         // WoT[o][c] (from regs)
    load_x_reg(Xg, wreg, tid);                               // issue X half0 loads
    __syncthreads();                     // B3
    if (tid < 128) {                     // u[o] = sum_c WoT[o][c]*t1[c] + bo[o]
        float s = 0.f;
        for (int c = 0; c < 128; ++c) s = fmaf((float)R1[tid * LD1 + c], t1b[c], s);
        ub[tid] = s + bo_g[tid];
    }
    zero_acc(acc);
    gemm_ab(R0, LD1, R1, LD1, 128, m0, n0, l15, quad, acc);  // Pt[c'][o]
    __syncthreads();                     // B4
    stage_ct_r1(acc, R1, LD1, m0, n0, l15, quad, gb, wb);    // Ps[o][c'] += wsum[o]*g[c']
    stage_x_from_reg(wreg, R0, tid);                         // X half0 -> R0 subtiled
    load_x_reg(Xg + 128, wreg, tid);                         // issue X half1 loads
    __syncthreads();                     // B5 (vmcnt(0) drain: half1 now in regs)
    zero_acc(acc);
    gemm_a_btr(R1, LD1, R0, m0, n0, l15, quad, acc);         // O[o][0:128]
    // store O'[h][o] for h in [0,128): f16x4 over 4 consecutive o
#pragma unroll
    for (int mt = 0; mt < 4; ++mt)
#pragma unroll
        for (int nt = 0; nt < 4; ++nt) {
            int h = n0 + nt * 16 + l15;
            int o = m0 + mt * 16 + quad * 4;
            f16x4 v;
#pragma unroll
            for (int r = 0; r < 4; ++r) v[r] = (f16)(acc[mt][nt][r] + ub[o + r]);
            *(f16x4*)(Xg + h * 128 + o) = v;
        }
    __syncthreads();                     // B6
    stage_x_from_reg(wreg, R0, tid);                         // X half1 -> R0 subtiled
    __syncthreads();                     // B7
    zero_acc(acc);
    gemm_a_btr(R1, LD1, R0, m0, n0, l15, quad, acc);         // O[o][128:256]
#pragma unroll
    for (int mt = 0; mt < 4; ++mt)
#pragma unroll
        for (int nt = 0; nt < 4; ++nt) {
            int h = 128 + n0 + nt * 16 + l15;
            int o = m0 + mt * 16 + quad * 4;
            f16x4 v;
#pragma unroll
            for (int r = 0; r < 4; ++r) v[r] = (f16)(acc[mt][nt][r] + ub[o + r]);
            *(f16x4*)(Xg + h * 128 + o) = v;
        }
}

extern "C" void kernel_launch(void* const* d_in, const int* in_sizes, int n_in,
                              void* d_out, int out_size, void* d_ws, size_t ws_size,
                              hipStream_t stream) {
    const float* x  = (const float*)d_in[0];
    const float* Wq = (const float*)d_in[1];
    const float* bq = (const float*)d_in[2];
    const float* Wk = (const float*)d_in[3];
    const float* bk = (const float*)d_in[4];
    const float* Wv = (const float*)d_in[5];
    const float* bv = (const float*)d_in[6];
    const float* Wn = (const float*)d_in[7];
    const float* bn = (const float*)d_in[8];
    const float* Wo = (const float*)d_in[9];
    const float* bo = (const float*)d_in[10];
    float* out = (float*)d_out;

    f16*   wsX = (f16*)d_ws;                                        // (B,W,C,H) f16: 134217728 B
    f16*   wsS = (f16*)((char*)d_ws + 134217728);                   // scores f16: 67108864 B
    float* wsV = (float*)((char*)d_ws + 134217728 + 67108864);      // h1/g/wsum/s0: 2KB
    float* wsZ = (float*)((char*)d_ws + 268435456);                 // softmax z: 1 MB
    f16*   wsW = (f16*)((char*)d_ws + 268435456 + 1048576);         // packed weights: 160 KB

    prep_w<<<192, 256, 0, stream>>>(Wq, Wk, Wo, wsW);
    prep_mv<<<1, 512, 0, stream>>>(Wn, Wv, Wo, bn, bv, wsW, wsV);
    t1_k<<<BB * CC * 4 * 2, 256, 0, stream>>>(x, wsX);
    p1_kernel<<<dim3(WW, BB), 256, 0, stream>>>(wsX, wsW, Wq, bq, Wk, bk, wsS);
    p2_kernel<<<(BB * CC * CC) / 512, 256, 0, stream>>>(wsS, wsZ);
    p3_kernel<<<dim3(WW, BB), 256, 0, stream>>>(wsX, wsS, wsZ, wsW, wsV, bo);
    t2_k<<<BB * 256 * 2 * 2, 256, 0, stream>>>(wsX, out);
}